// Round 3
// baseline (844.120 us; speedup 1.0000x reference)
//
#include <hip/hip_runtime.h>

#define B 64
#define L 512
#define D 256
#define F 256
#define T 4096
#define LN_EPS 1e-5f

// ---------------- Kernel 1: per-batch inclusive cumsum of durations ----------------
__global__ __launch_bounds__(64) void cumsum_kernel(const int* __restrict__ target,
                                                    int* __restrict__ ends) {
    int b = blockIdx.x;
    int lane = threadIdx.x;  // 64 lanes, 1 wave
    const int* trow = target + b * L;
    int* erow = ends + b * L;
    int vals[8];
    int base = lane * 8;
#pragma unroll
    for (int j = 0; j < 8; ++j) vals[j] = trow[base + j];
#pragma unroll
    for (int j = 1; j < 8; ++j) vals[j] += vals[j - 1];
    int lsum = vals[7];
    // inclusive wave scan of per-lane sums
    int s = lsum;
#pragma unroll
    for (int off = 1; off < 64; off <<= 1) {
        int v = __shfl_up(s, off, 64);
        if (lane >= off) s += v;
    }
    int excl = s - lsum;
#pragma unroll
    for (int j = 0; j < 8; ++j) erow[base + j] = excl + vals[j];
}

// ---------------- Kernel 2/3: fused conv1d(k=3) + LayerNorm + ReLU [+ linear] ----------------
// Block: 256 threads, handles 32 consecutive L-rows of one batch. Thread owns channel f=tid.
template <bool FUSE_LINEAR>
__global__ __launch_bounds__(256, 3) void conv_ln_relu_kernel(
    const float* __restrict__ xin,   // (B, L, 256)
    const float* __restrict__ w,     // (3, 256, 256)  [k][d][f]
    const float* __restrict__ bias,  // (256)
    const float* __restrict__ g,     // (256)
    const float* __restrict__ beta,  // (256)
    const float* __restrict__ lin_w, // (256) or null
    const float* __restrict__ lin_b, // (1) or null
    float* __restrict__ out)         // (B,L,256) hidden  OR  (B,L) dp_out
{
    __shared__ float xs[34][256];
    __shared__ float psum[32][4];
    __shared__ float psq[32][4];
    __shared__ float pdp[32][4];

    const int tid = threadIdx.x;
    const int b = blockIdx.y;
    const int l0 = blockIdx.x * 32;

    // stage x halo tile (rows l0-1 .. l0+32), zero-padded at batch edges
#pragma unroll
    for (int i = 0; i < 34; ++i) {
        int l = l0 - 1 + i;
        float v = 0.f;
        if (l >= 0 && l < L) v = xin[(b * L + l) * D + tid];
        xs[i][tid] = v;
    }
    __syncthreads();

    float acc[32];
    {
        float bv = bias[tid];
#pragma unroll
        for (int r = 0; r < 32; ++r) acc[r] = bv;
    }

    const float* w0p = w + 0 * 256 * 256 + tid;
    const float* w1p = w + 1 * 256 * 256 + tid;
    const float* w2p = w + 2 * 256 * 256 + tid;

    for (int d = 0; d < 256; d += 2) {
        float2 xv[34];
#pragma unroll
        for (int i = 0; i < 34; ++i) xv[i] = *(const float2*)&xs[i][d];
        float w00 = w0p[(d + 0) * 256];
        float w01 = w0p[(d + 1) * 256];
        float w10 = w1p[(d + 0) * 256];
        float w11 = w1p[(d + 1) * 256];
        float w20 = w2p[(d + 0) * 256];
        float w21 = w2p[(d + 1) * 256];
#pragma unroll
        for (int r = 0; r < 32; ++r) {
            float a = acc[r];
            a = fmaf(xv[r].x, w00, a);
            a = fmaf(xv[r].y, w01, a);
            a = fmaf(xv[r + 1].x, w10, a);
            a = fmaf(xv[r + 1].y, w11, a);
            a = fmaf(xv[r + 2].x, w20, a);
            a = fmaf(xv[r + 2].y, w21, a);
            acc[r] = a;
        }
    }

    // ---- LayerNorm over f (256 threads = 4 waves) ----
    const int lane = tid & 63;
    const int wid = tid >> 6;

#pragma unroll
    for (int r = 0; r < 32; ++r) {
        float v = acc[r];
        float s = v, q = v * v;
#pragma unroll
        for (int off = 32; off >= 1; off >>= 1) {
            s += __shfl_xor(s, off, 64);
            q += __shfl_xor(q, off, 64);
        }
        if (lane == 0) { psum[r][wid] = s; psq[r][wid] = q; }
    }
    __syncthreads();

    float gv = g[tid];
    float betav = beta[tid];
    float lwv = 0.f;
    if constexpr (FUSE_LINEAR) lwv = lin_w[tid];

#pragma unroll
    for (int r = 0; r < 32; ++r) {
        float s = psum[r][0] + psum[r][1] + psum[r][2] + psum[r][3];
        float q = psq[r][0] + psq[r][1] + psq[r][2] + psq[r][3];
        float mu = s * (1.f / 256.f);
        float var = q * (1.f / 256.f) - mu * mu;
        float rstd = rsqrtf(var + LN_EPS);
        float y = (acc[r] - mu) * rstd * gv + betav;
        y = fmaxf(y, 0.f);
        if constexpr (FUSE_LINEAR) {
            float p = y * lwv;
#pragma unroll
            for (int off = 32; off >= 1; off >>= 1) p += __shfl_xor(p, off, 64);
            if (lane == 0) pdp[r][wid] = p;
        } else {
            out[(b * L + l0 + r) * F + tid] = y;
        }
    }
    if constexpr (FUSE_LINEAR) {
        __syncthreads();
        if (tid < 32) {
            float p = pdp[tid][0] + pdp[tid][1] + pdp[tid][2] + pdp[tid][3] + lin_b[0];
            out[b * L + l0 + tid] = fmaxf(p, 0.f);
        }
    }
}

// ---------------- Kernel 4: length regulate (gather + mask) ----------------
// 1 wave per output row t; binary search of t in ends[b]; 1 KiB float4 copy.
__global__ __launch_bounds__(256) void length_regulate_kernel(
    const float* __restrict__ x, const int* __restrict__ ends, float* __restrict__ out) {
    const int tid = threadIdx.x;
    const int wid = tid >> 6;
    const int lane = tid & 63;
    const int b = blockIdx.y;
    const int t = blockIdx.x * 4 + wid;
    const int* e = ends + b * L;
    const int total = e[L - 1];
    float4 val = make_float4(0.f, 0.f, 0.f, 0.f);
    if (t < total) {
        int lo = 0, hi = L;  // upper_bound: first idx with e[idx] > t
        while (lo < hi) {
            int mid = (lo + hi) >> 1;
            if (e[mid] <= t) lo = mid + 1; else hi = mid;
        }
        int idx = min(lo, L - 1);
        val = *(const float4*)&x[(b * L + idx) * D + lane * 4];
    }
    *(float4*)&out[((size_t)(b * T + t)) * D + lane * 4] = val;
}

extern "C" void kernel_launch(void* const* d_in, const int* in_sizes, int n_in,
                              void* d_out, int out_size, void* d_ws, size_t ws_size,
                              hipStream_t stream) {
    const float* x   = (const float*)d_in[0];
    const int* target = (const int*)d_in[1];
    // d_in[2] = mel_max_length (4096, fixed by shapes)
    const float* c1w = (const float*)d_in[3];
    const float* c1b = (const float*)d_in[4];
    const float* g1  = (const float*)d_in[5];
    const float* b1  = (const float*)d_in[6];
    const float* c2w = (const float*)d_in[7];
    const float* c2b = (const float*)d_in[8];
    const float* g2  = (const float*)d_in[9];
    const float* b2  = (const float*)d_in[10];
    const float* lw  = (const float*)d_in[11];
    const float* lb  = (const float*)d_in[12];

    float* out = (float*)d_out;                 // (B,T,D)
    float* dp  = out + (size_t)B * T * D;       // (B,L)

    // Scratch: ends (128 KiB) in d_ws; h1 (33.5 MiB) staged inside the output
    // region (conv1 writes it, conv2 reads it, length_regulate overwrites it
    // afterwards — same-stream ordering makes this safe).
    int* ends = (int*)d_ws;       // B*L ints
    float* h1 = out;              // (B,L,F) floats, temporary

    cumsum_kernel<<<dim3(B), dim3(64), 0, stream>>>(target, ends);
    conv_ln_relu_kernel<false><<<dim3(L / 32, B), dim3(256), 0, stream>>>(
        x, c1w, c1b, g1, b1, nullptr, nullptr, h1);
    conv_ln_relu_kernel<true><<<dim3(L / 32, B), dim3(256), 0, stream>>>(
        h1, c2w, c2b, g2, b2, lw, lb, dp);
    length_regulate_kernel<<<dim3(T / 4, B), dim3(256), 0, stream>>>(x, ends, out);
}

// Round 6
// 504.328 us; speedup vs baseline: 1.6738x; 1.6738x over previous
//
#include <hip/hip_runtime.h>

#define B 64
#define L 512
#define D 256
#define T 4096
#define LN_EPS 1e-5f

typedef __attribute__((ext_vector_type(8))) short bf16x8;
typedef __attribute__((ext_vector_type(4))) float f32x4;
typedef __attribute__((ext_vector_type(4))) unsigned short u16x4;

__device__ __forceinline__ unsigned short f2bf(float f) {
    unsigned int u = __float_as_uint(f);
    unsigned int r = (u + 0x7FFFu + ((u >> 16) & 1u)) >> 16;  // RNE
    return (unsigned short)r;
}

// ---------------- convert x (fp32) -> bf16 ----------------
__global__ __launch_bounds__(256) void cvt_x_kernel(const float* __restrict__ in,
                                                    unsigned short* __restrict__ out) {
    const int n4 = B * L * D / 4;
    for (int i = blockIdx.x * 256 + threadIdx.x; i < n4; i += gridDim.x * 256) {
        float4 v = ((const float4*)in)[i];
        u16x4 o = {f2bf(v.x), f2bf(v.y), f2bf(v.z), f2bf(v.w)};
        *(u16x4*)(out + i * 4) = o;
    }
}

// ---------------- convert+transpose w[k][d][f] -> wT[k][f][d] (bf16) ----------------
__global__ __launch_bounds__(256) void cvt_w_kernel(const float* __restrict__ w1,
                                                    const float* __restrict__ w2,
                                                    unsigned short* __restrict__ o1,
                                                    unsigned short* __restrict__ o2) {
    const float* in = blockIdx.y ? w2 : w1;
    unsigned short* out = blockIdx.y ? o2 : o1;
    const int k = blockIdx.x;        // 0..2
    const int d0 = blockIdx.z * 32;  // 8 chunks
    const int f = threadIdx.x;
    for (int dc = 0; dc < 32; dc += 8) {
        unsigned short v[8];
#pragma unroll
        for (int i = 0; i < 8; ++i) v[i] = f2bf(in[(k * 256 + d0 + dc + i) * 256 + f]);
        *(bf16x8*)(out + (k * 256 + f) * 256 + d0 + dc) = *(bf16x8*)v;
    }
}

// ---------------- per-batch inclusive cumsum ----------------
__global__ __launch_bounds__(64) void cumsum_kernel(const int* __restrict__ target,
                                                    int* __restrict__ ends) {
    int b = blockIdx.x;
    int lane = threadIdx.x;
    const int* trow = target + b * L;
    int* erow = ends + b * L;
    int vals[8];
    int base = lane * 8;
#pragma unroll
    for (int j = 0; j < 8; ++j) vals[j] = trow[base + j];
#pragma unroll
    for (int j = 1; j < 8; ++j) vals[j] += vals[j - 1];
    int lsum = vals[7];
    int s = lsum;
#pragma unroll
    for (int off = 1; off < 64; off <<= 1) {
        int v = __shfl_up(s, off, 64);
        if (lane >= off) s += v;
    }
    int excl = s - lsum;
#pragma unroll
    for (int j = 0; j < 8; ++j) erow[base + j] = excl + vals[j];
}

// ---------------- MFMA conv1d(k=3,256->256) -> fp32 y = conv + bias ----------------
// Block: 256 thr = 4 waves, tile 64(M) x 256(N), K = 3*256. Wave tile 32x128 (2x8 frags).
// Linear LDS with +8 element pad (stride 264): 2-way bank aliasing only (free).
__global__ __launch_bounds__(256, 2) void conv_gemm_kernel(
    const unsigned short* __restrict__ xin,  // bf16 (B,512,256)
    const unsigned short* __restrict__ wT,   // bf16 (3,256,256) [k][f][d]
    const float* __restrict__ bias,
    float* __restrict__ y)                   // fp32 (B,512,256)
{
    constexpr int LS = 264;  // LDS row stride in bf16 elements
    __shared__ __align__(16) unsigned short xs[66 * LS];

    const int tid = threadIdx.x;
    const int lane = tid & 63;
    const int wid = tid >> 6;
    const int l15 = lane & 15;
    const int g4 = lane >> 4;
    const int b = blockIdx.y;
    const int l0 = blockIdx.x * 64;
    const int wm = (wid >> 1) * 32;   // wave M offset
    const int wn = (wid & 1) * 128;   // wave N offset

    // stage x rows l0-1 .. l0+64 into LDS (linear, padded stride)
    for (int i = tid; i < 66 * 32; i += 256) {
        int r = i >> 5, c = i & 31;
        int grow = l0 - 1 + r;
        bf16x8 v = {0, 0, 0, 0, 0, 0, 0, 0};
        if (grow >= 0 && grow < L) v = *(const bf16x8*)(xin + ((size_t)(b * L + grow)) * D + c * 8);
        *(bf16x8*)(xs + r * LS + c * 8) = v;
    }
    __syncthreads();

    f32x4 acc[2][8];
#pragma unroll
    for (int m = 0; m < 2; ++m)
#pragma unroll
        for (int n = 0; n < 8; ++n) acc[m][n] = (f32x4){0.f, 0.f, 0.f, 0.f};

#pragma unroll 4
    for (int ks = 0; ks < 24; ++ks) {
        const int tap = ks >> 3, kk = ks & 7;
        const int r0 = wm + l15 + tap;
        bf16x8 a0 = *(const bf16x8*)(xs + r0 * LS + kk * 32 + g4 * 8);
        bf16x8 a1 = *(const bf16x8*)(xs + (r0 + 16) * LS + kk * 32 + g4 * 8);
        const unsigned short* wp = wT + tap * 65536 + (wn + l15) * 256 + kk * 32 + g4 * 8;
#pragma unroll
        for (int n = 0; n < 8; ++n) {
            bf16x8 bf = *(const bf16x8*)(wp + n * 4096);
            acc[0][n] = __builtin_amdgcn_mfma_f32_16x16x32_bf16(a0, bf, acc[0][n], 0, 0, 0);
            acc[1][n] = __builtin_amdgcn_mfma_f32_16x16x32_bf16(a1, bf, acc[1][n], 0, 0, 0);
        }
    }

    // epilogue: y[row][col] = acc + bias[col]  (C/D: col=lane&15, row=(lane>>4)*4+reg)
    float biasv[8];
#pragma unroll
    for (int n = 0; n < 8; ++n) biasv[n] = bias[wn + n * 16 + l15];

#pragma unroll
    for (int m = 0; m < 2; ++m)
#pragma unroll
        for (int j = 0; j < 4; ++j) {
            int row = wm + m * 16 + g4 * 4 + j;
            size_t base = ((size_t)(b * L + l0 + row)) * D + wn + l15;
#pragma unroll
            for (int n = 0; n < 8; ++n) y[base + n * 16] = acc[m][n][j] + biasv[n];
        }
}

// ---------------- LayerNorm + ReLU (fp32 in, bf16 out) — round-3-proven reduce ----------------
__global__ __launch_bounds__(256) void ln_relu_kernel(
    const float* __restrict__ y, const float* __restrict__ g, const float* __restrict__ beta,
    unsigned short* __restrict__ h) {
    __shared__ float ps[8][4], pq[8][4];
    const int tid = threadIdx.x;
    const int lane = tid & 63, wid = tid >> 6;
    const int row0 = blockIdx.x * 8;
    float gv = g[tid], bv = beta[tid];
    float val[8];
#pragma unroll
    for (int r = 0; r < 8; ++r) {
        float v = y[(size_t)(row0 + r) * 256 + tid];
        val[r] = v;
        float s = v, q = v * v;
#pragma unroll
        for (int off = 32; off >= 1; off >>= 1) {
            s += __shfl_xor(s, off, 64);
            q += __shfl_xor(q, off, 64);
        }
        if (lane == 0) { ps[r][wid] = s; pq[r][wid] = q; }
    }
    __syncthreads();
#pragma unroll
    for (int r = 0; r < 8; ++r) {
        float s = ps[r][0] + ps[r][1] + ps[r][2] + ps[r][3];
        float q = pq[r][0] + pq[r][1] + pq[r][2] + pq[r][3];
        float mu = s * (1.f / 256.f);
        float var = q * (1.f / 256.f) - mu * mu;
        float rstd = rsqrtf(var + LN_EPS);
        float out = fmaxf((val[r] - mu) * rstd * gv + bv, 0.f);
        h[(size_t)(row0 + r) * 256 + tid] = f2bf(out);
    }
}

// ---------------- LayerNorm + ReLU + linear(256->1) + ReLU -> dp (all fp32) ----------------
__global__ __launch_bounds__(256) void ln_dp_kernel(
    const float* __restrict__ y, const float* __restrict__ g, const float* __restrict__ beta,
    const float* __restrict__ lin_w, const float* __restrict__ lin_b,
    float* __restrict__ dp) {
    __shared__ float ps[8][4], pq[8][4], pdp[8][4];
    const int tid = threadIdx.x;
    const int lane = tid & 63, wid = tid >> 6;
    const int row0 = blockIdx.x * 8;
    float gv = g[tid], bv = beta[tid], lwv = lin_w[tid];
    float val[8];
#pragma unroll
    for (int r = 0; r < 8; ++r) {
        float v = y[(size_t)(row0 + r) * 256 + tid];
        val[r] = v;
        float s = v, q = v * v;
#pragma unroll
        for (int off = 32; off >= 1; off >>= 1) {
            s += __shfl_xor(s, off, 64);
            q += __shfl_xor(q, off, 64);
        }
        if (lane == 0) { ps[r][wid] = s; pq[r][wid] = q; }
    }
    __syncthreads();
#pragma unroll
    for (int r = 0; r < 8; ++r) {
        float s = ps[r][0] + ps[r][1] + ps[r][2] + ps[r][3];
        float q = pq[r][0] + pq[r][1] + pq[r][2] + pq[r][3];
        float mu = s * (1.f / 256.f);
        float var = q * (1.f / 256.f) - mu * mu;
        float rstd = rsqrtf(var + LN_EPS);
        float p = fmaxf((val[r] - mu) * rstd * gv + bv, 0.f) * lwv;
#pragma unroll
        for (int off = 32; off >= 1; off >>= 1) p += __shfl_xor(p, off, 64);
        if (lane == 0) pdp[r][wid] = p;
    }
    __syncthreads();
    if (tid < 8)
        dp[row0 + tid] = fmaxf(pdp[tid][0] + pdp[tid][1] + pdp[tid][2] + pdp[tid][3] + lin_b[0], 0.f);
}

// ---------------- length regulate: 256 t-rows/block, parallel searches + float4 copy ----------------
__global__ __launch_bounds__(256) void length_regulate_kernel(
    const float* __restrict__ x, const int* __restrict__ ends, float* __restrict__ out) {
    __shared__ int sidx[256];
    const int tid = threadIdx.x;
    const int lane = tid & 63;
    const int wid = tid >> 6;
    const int b = blockIdx.y;
    const int t0 = blockIdx.x * 256;
    const int* e = ends + b * L;
    const int total = e[L - 1];
    {
        int t = t0 + tid;
        int lo = 0, hi = L;
        while (lo < hi) {
            int mid = (lo + hi) >> 1;
            if (e[mid] <= t) lo = mid + 1; else hi = mid;
        }
        sidx[tid] = (lo < L - 1) ? lo : (L - 1);
    }
    __syncthreads();
    const float4* x4 = (const float4*)(x + (size_t)b * L * D);
    float4* o4 = (float4*)(out + (size_t)b * T * D);
    const float4 z = make_float4(0.f, 0.f, 0.f, 0.f);
#pragma unroll 4
    for (int rr = 0; rr < 64; ++rr) {
        int row = wid * 64 + rr;
        int t = t0 + row;
        float4 v = z;
        if (t < total) v = x4[sidx[row] * 64 + lane];
        o4[t * 64 + lane] = v;
    }
}

extern "C" void kernel_launch(void* const* d_in, const int* in_sizes, int n_in,
                              void* d_out, int out_size, void* d_ws, size_t ws_size,
                              hipStream_t stream) {
    const float* x   = (const float*)d_in[0];
    const int* target = (const int*)d_in[1];
    const float* c1w = (const float*)d_in[3];
    const float* c1b = (const float*)d_in[4];
    const float* g1  = (const float*)d_in[5];
    const float* b1  = (const float*)d_in[6];
    const float* c2w = (const float*)d_in[7];
    const float* c2b = (const float*)d_in[8];
    const float* g2  = (const float*)d_in[9];
    const float* b2  = (const float*)d_in[10];
    const float* lw  = (const float*)d_in[11];
    const float* lb  = (const float*)d_in[12];

    float* out = (float*)d_out;                    // (B,T,D)
    float* dp  = out + (size_t)B * T * D;          // (B,L)

    // Scratch staged inside d_out's (B,T,D) region (256 MiB); all consumed before
    // length_regulate (the last kernel) overwrites it. Stream-serialized.
    char* base = (char*)d_out;
    unsigned short* x_bf = (unsigned short*)(base);              // 16 MiB @ 0
    unsigned short* h1   = (unsigned short*)(base + (16u << 20));  // 16 MiB @ 16M
    float* y32           = (float*)(base + (32u << 20));           // 32 MiB @ 32M
    unsigned short* wT1  = (unsigned short*)(base + (64u << 20));  // @64M
    unsigned short* wT2  = (unsigned short*)(base + (64u << 20) + 393216);
    int* ends = (int*)d_ws;  // B*L ints

    cvt_x_kernel<<<dim3(4096), dim3(256), 0, stream>>>(x, x_bf);
    cvt_w_kernel<<<dim3(3, 2, 8), dim3(256), 0, stream>>>(c1w, c2w, wT1, wT2);
    cumsum_kernel<<<dim3(B), dim3(64), 0, stream>>>(target, ends);

    conv_gemm_kernel<<<dim3(L / 64, B), dim3(256), 0, stream>>>(x_bf, wT1, c1b, y32);
    ln_relu_kernel<<<dim3(B * L / 8), dim3(256), 0, stream>>>(y32, g1, b1, h1);
    conv_gemm_kernel<<<dim3(L / 64, B), dim3(256), 0, stream>>>(h1, wT2, c2b, y32);
    ln_dp_kernel<<<dim3(B * L / 8), dim3(256), 0, stream>>>(y32, g2, b2, lw, lb, dp);

    length_regulate_kernel<<<dim3(T / 256, B), dim3(256), 0, stream>>>(x, ends, out);
}

// Round 7
// 445.477 us; speedup vs baseline: 1.8949x; 1.1321x over previous
//
#include <hip/hip_runtime.h>

#define B 64
#define L 512
#define D 256
#define T 4096
#define LN_EPS 1e-5f

typedef __attribute__((ext_vector_type(8))) short bf16x8;
typedef __attribute__((ext_vector_type(4))) float f32x4;

__device__ __forceinline__ unsigned short f2bf(float f) {
    unsigned int u = __float_as_uint(f);
    unsigned int r = (u + 0x7FFFu + ((u >> 16) & 1u)) >> 16;  // RNE
    return (unsigned short)r;
}

// ---------------- convert+transpose w[k][d][f] -> wT[k][f][d] (bf16) ----------------
__global__ __launch_bounds__(256) void cvt_w_kernel(const float* __restrict__ w1,
                                                    const float* __restrict__ w2,
                                                    unsigned short* __restrict__ o1,
                                                    unsigned short* __restrict__ o2) {
    const float* in = blockIdx.y ? w2 : w1;
    unsigned short* out = blockIdx.y ? o2 : o1;
    const int k = blockIdx.x;        // 0..2
    const int d0 = blockIdx.z * 32;  // 8 chunks
    const int f = threadIdx.x;
    for (int dc = 0; dc < 32; dc += 8) {
        unsigned short v[8];
#pragma unroll
        for (int i = 0; i < 8; ++i) v[i] = f2bf(in[(k * 256 + d0 + dc + i) * 256 + f]);
        *(bf16x8*)(out + (k * 256 + f) * 256 + d0 + dc) = *(bf16x8*)v;
    }
}

// ---------------- per-batch inclusive cumsum ----------------
__global__ __launch_bounds__(64) void cumsum_kernel(const int* __restrict__ target,
                                                    int* __restrict__ ends) {
    int b = blockIdx.x;
    int lane = threadIdx.x;
    const int* trow = target + b * L;
    int* erow = ends + b * L;
    int vals[8];
    int base = lane * 8;
#pragma unroll
    for (int j = 0; j < 8; ++j) vals[j] = trow[base + j];
#pragma unroll
    for (int j = 1; j < 8; ++j) vals[j] += vals[j - 1];
    int lsum = vals[7];
    int s = lsum;
#pragma unroll
    for (int off = 1; off < 64; off <<= 1) {
        int v = __shfl_up(s, off, 64);
        if (lane >= off) s += v;
    }
    int excl = s - lsum;
#pragma unroll
    for (int j = 0; j < 8; ++j) erow[base + j] = excl + vals[j];
}

// ---------------- MFMA conv1d(k=3,256->256) + LN + ReLU [+ linear->dp], fused ----------------
// Block: 256 thr = 4 waves, tile 64(M) x 256(N), K = 3*256. Wave tile 32x128 (2x8 frags).
// Linear LDS, stride 264 (+8 pad): row-stride 528 B -> banks rotate by 4/row, ~2-way only.
// IN_F32: read fp32 input and convert to bf16 during LDS staging (conv1).
template <bool IN_F32, bool FUSE_LINEAR>
__global__ __launch_bounds__(256, 2) void conv_fused_kernel(
    const void* __restrict__ xin,            // fp32 (B,512,256) if IN_F32 else bf16
    const unsigned short* __restrict__ wT,   // bf16 (3,256,256) [k][f][d]
    const float* __restrict__ bias, const float* __restrict__ g, const float* __restrict__ beta,
    const float* __restrict__ lin_w, const float* __restrict__ lin_b,
    unsigned short* __restrict__ hout,  // bf16 (B,512,256) out (conv1)
    float* __restrict__ dp)             // fp32 (B,512) out (conv2)
{
    constexpr int LS = 264;  // LDS row stride in bf16 elements
    __shared__ __align__(16) unsigned short xs[66 * LS];
    __shared__ float psum[64][2];
    __shared__ float psq[64][2];
    __shared__ float muA[64], rsA[64];

    const int tid = threadIdx.x;
    const int lane = tid & 63;
    const int wid = tid >> 6;
    const int l15 = lane & 15;
    const int g4 = lane >> 4;
    const int b = blockIdx.y;
    const int l0 = blockIdx.x * 64;
    const int wm = (wid >> 1) * 32;   // wave M offset
    const int wn = (wid & 1) * 128;   // wave N offset

    // ---- stage x rows l0-1 .. l0+64 into LDS (convert fp32->bf16 if IN_F32) ----
    for (int i = tid; i < 66 * 32; i += 256) {
        int r = i >> 5, c = i & 31;
        int grow = l0 - 1 + r;
        bf16x8 v = {0, 0, 0, 0, 0, 0, 0, 0};
        if (grow >= 0 && grow < L) {
            if constexpr (IN_F32) {
                const float* xr = (const float*)xin + ((size_t)(b * L + grow)) * D + c * 8;
                float4 f0 = *(const float4*)xr;
                float4 f1 = *(const float4*)(xr + 4);
                unsigned short t[8] = {f2bf(f0.x), f2bf(f0.y), f2bf(f0.z), f2bf(f0.w),
                                       f2bf(f1.x), f2bf(f1.y), f2bf(f1.z), f2bf(f1.w)};
                v = *(bf16x8*)t;
            } else {
                v = *(const bf16x8*)((const unsigned short*)xin + ((size_t)(b * L + grow)) * D + c * 8);
            }
        }
        *(bf16x8*)(xs + r * LS + c * 8) = v;
    }
    __syncthreads();

    f32x4 acc[2][8];
#pragma unroll
    for (int m = 0; m < 2; ++m)
#pragma unroll
        for (int n = 0; n < 8; ++n) acc[m][n] = (f32x4){0.f, 0.f, 0.f, 0.f};

#pragma unroll 4
    for (int ks = 0; ks < 24; ++ks) {
        const int tap = ks >> 3, kk = ks & 7;
        const int r0 = wm + l15 + tap;
        bf16x8 a0 = *(const bf16x8*)(xs + r0 * LS + kk * 32 + g4 * 8);
        bf16x8 a1 = *(const bf16x8*)(xs + (r0 + 16) * LS + kk * 32 + g4 * 8);
        const unsigned short* wp = wT + tap * 65536 + (wn + l15) * 256 + kk * 32 + g4 * 8;
#pragma unroll
        for (int n = 0; n < 8; ++n) {
            bf16x8 bf = *(const bf16x8*)(wp + n * 4096);
            acc[0][n] = __builtin_amdgcn_mfma_f32_16x16x32_bf16(a0, bf, acc[0][n], 0, 0, 0);
            acc[1][n] = __builtin_amdgcn_mfma_f32_16x16x32_bf16(a1, bf, acc[1][n], 0, 0, 0);
        }
    }

    // ---- epilogue constants (per-lane cols: wn + n*16 + l15) ----
    float biasv[8], gv[8], bv[8], lwv[8];
#pragma unroll
    for (int n = 0; n < 8; ++n) {
        int col = wn + n * 16 + l15;
        biasv[n] = bias[col];
        gv[n] = g[col];
        bv[n] = beta[col];
        lwv[n] = FUSE_LINEAR ? lin_w[col] : 0.f;
    }

    // ---- LN stats: per-row sum/sumsq (row = wm + m*16 + g4*4 + j; C/D col=l15) ----
#pragma unroll
    for (int m = 0; m < 2; ++m)
#pragma unroll
        for (int j = 0; j < 4; ++j) {
            float s = 0.f, q = 0.f;
#pragma unroll
            for (int n = 0; n < 8; ++n) {
                float v = acc[m][n][j] + biasv[n];
                s += v;
                q += v * v;
            }
#pragma unroll
            for (int off = 1; off < 16; off <<= 1) {
                s += __shfl_xor(s, off, 64);
                q += __shfl_xor(q, off, 64);
            }
            if (l15 == 0) {
                int row = wm + m * 16 + g4 * 4 + j;
                psum[row][wid & 1] = s;
                psq[row][wid & 1] = q;
            }
        }
    __syncthreads();
    if (tid < 64) {
        float s = psum[tid][0] + psum[tid][1];
        float q = psq[tid][0] + psq[tid][1];
        float mu = s * (1.f / 256.f);
        float var = q * (1.f / 256.f) - mu * mu;
        muA[tid] = mu;
        rsA[tid] = rsqrtf(var + LN_EPS);
    }
    __syncthreads();

    if constexpr (!FUSE_LINEAR) {
#pragma unroll
        for (int m = 0; m < 2; ++m)
#pragma unroll
            for (int j = 0; j < 4; ++j) {
                int row = wm + m * 16 + g4 * 4 + j;
                float mu = muA[row], rs = rsA[row];
                size_t base = ((size_t)(b * L + l0 + row)) * D + wn + l15;
#pragma unroll
                for (int n = 0; n < 8; ++n) {
                    float v = acc[m][n][j] + biasv[n];
                    float y = fmaxf((v - mu) * rs * gv[n] + bv[n], 0.f);
                    hout[base + n * 16] = f2bf(y);
                }
            }
    } else {
        float lb0 = lin_b[0];
#pragma unroll
        for (int m = 0; m < 2; ++m)
#pragma unroll
            for (int j = 0; j < 4; ++j) {
                int row = wm + m * 16 + g4 * 4 + j;
                float mu = muA[row], rs = rsA[row];
                float p = 0.f;
#pragma unroll
                for (int n = 0; n < 8; ++n) {
                    float v = acc[m][n][j] + biasv[n];
                    float y = fmaxf((v - mu) * rs * gv[n] + bv[n], 0.f);
                    p += y * lwv[n];
                }
#pragma unroll
                for (int off = 1; off < 16; off <<= 1) p += __shfl_xor(p, off, 64);
                if (l15 == 0) psum[row][wid & 1] = p;
            }
        __syncthreads();
        if (tid < 64) dp[b * L + l0 + tid] = fmaxf(psum[tid][0] + psum[tid][1] + lb0, 0.f);
    }
}

// ---------------- length regulate: 256 t-rows/block, parallel searches + float4 copy ----------------
__global__ __launch_bounds__(256) void length_regulate_kernel(
    const float* __restrict__ x, const int* __restrict__ ends, float* __restrict__ out) {
    __shared__ int sidx[256];
    const int tid = threadIdx.x;
    const int lane = tid & 63;
    const int wid = tid >> 6;
    const int b = blockIdx.y;
    const int t0 = blockIdx.x * 256;
    const int* e = ends + b * L;
    const int total = e[L - 1];
    {
        int t = t0 + tid;
        int lo = 0, hi = L;
        while (lo < hi) {
            int mid = (lo + hi) >> 1;
            if (e[mid] <= t) lo = mid + 1; else hi = mid;
        }
        sidx[tid] = (lo < L - 1) ? lo : (L - 1);
    }
    __syncthreads();
    const float4* x4 = (const float4*)(x + (size_t)b * L * D);
    float4* o4 = (float4*)(out + (size_t)b * T * D);
    const float4 z = make_float4(0.f, 0.f, 0.f, 0.f);
#pragma unroll 4
    for (int rr = 0; rr < 64; ++rr) {
        int row = wid * 64 + rr;
        int t = t0 + row;
        float4 v = z;
        if (t < total) v = x4[sidx[row] * 64 + lane];
        o4[t * 64 + lane] = v;
    }
}

extern "C" void kernel_launch(void* const* d_in, const int* in_sizes, int n_in,
                              void* d_out, int out_size, void* d_ws, size_t ws_size,
                              hipStream_t stream) {
    const float* x   = (const float*)d_in[0];
    const int* target = (const int*)d_in[1];
    const float* c1w = (const float*)d_in[3];
    const float* c1b = (const float*)d_in[4];
    const float* g1  = (const float*)d_in[5];
    const float* b1  = (const float*)d_in[6];
    const float* c2w = (const float*)d_in[7];
    const float* c2b = (const float*)d_in[8];
    const float* g2  = (const float*)d_in[9];
    const float* b2  = (const float*)d_in[10];
    const float* lw  = (const float*)d_in[11];
    const float* lb  = (const float*)d_in[12];

    float* out = (float*)d_out;                    // (B,T,D)
    float* dp  = out + (size_t)B * T * D;          // (B,L)

    // Scratch inside d_out's (B,T,D) region (268 MB), consumed before the final
    // length_regulate overwrites it (stream-serialized):
    //   h1  @ 0       : 16,777,216 B  (bf16 B*L*D)
    //   wT1 @ 32 MiB  :    393,216 B
    //   wT2 @ 32 MiB + 393,216
    char* base = (char*)d_out;
    unsigned short* h1  = (unsigned short*)(base);
    unsigned short* wT1 = (unsigned short*)(base + (32u << 20));
    unsigned short* wT2 = (unsigned short*)(base + (32u << 20) + 393216);
    int* ends = (int*)d_ws;  // B*L ints

    cvt_w_kernel<<<dim3(3, 2, 8), dim3(256), 0, stream>>>(c1w, c2w, wT1, wT2);
    cumsum_kernel<<<dim3(B), dim3(64), 0, stream>>>(target, ends);
    conv_fused_kernel<true, false><<<dim3(L / 64, B), dim3(256), 0, stream>>>(
        x, wT1, c1b, g1, b1, nullptr, nullptr, h1, nullptr);
    conv_fused_kernel<false, true><<<dim3(L / 64, B), dim3(256), 0, stream>>>(
        h1, wT2, c2b, g2, b2, lw, lb, nullptr, dp);
    length_regulate_kernel<<<dim3(T / 256, B), dim3(256), 0, stream>>>(x, ends, out);
}